// Round 4
// baseline (98.133 us; speedup 1.0000x reference)
//
#include <hip/hip_runtime.h>
#include <math.h>

#define NROWS 65536
#define DIM   256
#define NCLS  512
#define CPW   128                 // rows per class
#define BM    64                  // rows per k_main tile
#define NBLK  1024                // NROWS / BM

// ws layout (float offsets)
#define WS_CNT_I   0              // 512 ints
#define WS_IDX_I   512            // 65536 ints
#define WS_QPACK_F 66048          // 131072 u16 (256 KB)
#define WS_XB_F    131584         // 16,777,216 u16 (32 MB), 16B-aligned

typedef float f32x4  __attribute__((ext_vector_type(4)));
typedef short bf16x8 __attribute__((ext_vector_type(8)));
typedef unsigned short u16;

__device__ inline u16 f2bf(float f) {
  unsigned u = __float_as_uint(f);
  u += 0x7FFFu + ((u >> 16) & 1u);      // RNE (inputs finite)
  return (u16)(u >> 16);
}
__device__ inline unsigned pack2(float a, float b) {
  return (unsigned)f2bf(a) | ((unsigned)f2bf(b) << 16);
}

// ---------------- kernel 0: zero class cursors + output ----------------
__global__ __launch_bounds__(512) void k_zero(int* __restrict__ cnt,
                                              float* __restrict__ out) {
  cnt[threadIdx.x] = 0;
  if (threadIdx.x == 0) out[0] = 0.f;
}

// ---------------- kernel 1: scatter row indices by class ----------------
__global__ __launch_bounds__(256) void k_scatter(
    const int* __restrict__ tgt, int* __restrict__ cnt, int* __restrict__ idx) {
  const int row = blockIdx.x * 256 + threadIdx.x;
  const int c = tgt[row];
  const int p = atomicAdd(&cnt[c], 1);
  if (p < CPW) idx[c * CPW + p] = row;
}

// ---- kernel 2: per-class sums -> qpack B-frags; write normalized bf16 rows
// ---- to xb in ROW-MAJOR class-grouped order (contiguous full-line writes)
__global__ __launch_bounds__(512) void k_csum(
    const float* __restrict__ x, const int* __restrict__ idx,
    u16* __restrict__ qpack, u16* __restrict__ xb) {
  __shared__ int   sidx[CPW];
  __shared__ float wpart[8][DIM];     // 8 KB
  __shared__ float wsum[4];
  __shared__ float ninv_s;
  const int c    = blockIdx.x;
  const int tid  = threadIdx.x;
  const int w    = tid >> 6;
  const int lane = tid & 63;
  if (tid < CPW) sidx[tid] = idx[c * CPW + tid];
  __syncthreads();

  float4 vs = make_float4(0.f, 0.f, 0.f, 0.f);
  #pragma unroll 4
  for (int i = 0; i < 16; ++i) {
    const int rl  = w * 16 + i;
    const int row = sidx[rl];
    const float4 v = *reinterpret_cast<const float4*>(x + (size_t)row * DIM + lane * 4);
    vs.x += v.x; vs.y += v.y; vs.z += v.z; vs.w += v.w;
    float ss = v.x * v.x + v.y * v.y + v.z * v.z + v.w * v.w;
    ss += __shfl_xor(ss, 1, 64);
    ss += __shfl_xor(ss, 2, 64);
    ss += __shfl_xor(ss, 4, 64);
    ss += __shfl_xor(ss, 8, 64);
    ss += __shfl_xor(ss, 16, 64);
    ss += __shfl_xor(ss, 32, 64);
    const float rn = rsqrtf(fmaxf(ss, 1e-30f));
    uint2 u;
    u.x = pack2(v.x * rn, v.y * rn);
    u.y = pack2(v.z * rn, v.w * rn);
    // row-major, class-grouped slot order: wave writes 512B contiguous per row
    *reinterpret_cast<uint2*>(xb + ((size_t)c * CPW + rl) * DIM + lane * 4) = u;
  }
  *reinterpret_cast<float4*>(&wpart[w][lane * 4]) = vs;
  __syncthreads();

  float s = 0.f;
  if (tid < DIM) {
    #pragma unroll
    for (int ww = 0; ww < 8; ++ww) s += wpart[ww][tid];
  }
  float sq = s * s;
  sq += __shfl_xor(sq, 1, 64);
  sq += __shfl_xor(sq, 2, 64);
  sq += __shfl_xor(sq, 4, 64);
  sq += __shfl_xor(sq, 8, 64);
  sq += __shfl_xor(sq, 16, 64);
  sq += __shfl_xor(sq, 32, 64);
  if (tid < DIM && (tid & 63) == 0) wsum[tid >> 6] = sq;
  __syncthreads();
  if (tid == 0) ninv_s = rsqrtf(fmaxf(wsum[0] + wsum[1] + wsum[2] + wsum[3], 1e-30f));
  __syncthreads();
  if (tid < DIM)
    qpack[((tid >> 3) * NCLS + c) * 8 + (tid & 7)] = f2bf(s * ninv_s);
}

// --------- kernel 3: MFMA GEMM + max-free log-softmax + atomic loss ----------
// 8 waves, each 64 rows x 64 cols. Whole block shares target class blockIdx>>1.
// A staged from row-major xb via global_load_lds transpose-gather:
//   per-lane SOURCE (row = lane) does the row-major -> [kg][row][8] transpose,
//   LDS dest stays linear -> conflict-free ds_read_b128 (proven 0 conflicts).
__global__ __launch_bounds__(512) void k_main(
    const u16* __restrict__ xb, const u16* __restrict__ qpack,
    float* __restrict__ out) {
  __shared__ u16   Alds[32 * 64 * 8];   // 32 KB, [kg][row][8]
  __shared__ float psum[8][64];
  __shared__ float simt[64];

  const int tid  = threadIdx.x;
  const int t    = blockIdx.x;
  const int w    = tid >> 6;
  const int lane = tid & 63;

  // stage A tile: lane's row = t*64 + lane; instruction i picks kg = w*4+i
  const u16* xrow = xb + ((size_t)t * 64 + lane) * DIM;
  #pragma unroll
  for (int i = 0; i < 4; ++i) {
    const int kg = w * 4 + i;
    const u16* g = xrow + kg * 8;
    u16* l = &Alds[kg * 64 * 8];
    __builtin_amdgcn_global_load_lds(
        (const __attribute__((address_space(1))) unsigned*)g,
        (__attribute__((address_space(3))) unsigned*)l, 16, 0, 0);
  }
  __syncthreads();

  const int lg = lane >> 4, l15 = lane & 15;
  f32x4 acc[4][4];
  #pragma unroll
  for (int m = 0; m < 4; ++m)
    #pragma unroll
    for (int n = 0; n < 4; ++n) acc[m][n] = (f32x4)0.f;

  const bf16x8* ap = reinterpret_cast<const bf16x8*>(Alds);
  const bf16x8* bp = reinterpret_cast<const bf16x8*>(qpack);
  const int bbase = w * 64 + l15;       // + n*16

  bf16x8 b0[4], b1[4];
  #pragma unroll
  for (int n = 0; n < 4; ++n) b0[n] = bp[lg * NCLS + bbase + n * 16];

  #pragma unroll 1
  for (int kk = 0; kk < 8; kk += 2) {
    #pragma unroll
    for (int n = 0; n < 4; ++n)
      b1[n] = bp[((kk + 1) * 4 + lg) * NCLS + bbase + n * 16];
    {
      bf16x8 a[4];
      #pragma unroll
      for (int m = 0; m < 4; ++m) a[m] = ap[(kk * 4 + lg) * 64 + m * 16 + l15];
      #pragma unroll
      for (int m = 0; m < 4; ++m)
        #pragma unroll
        for (int n = 0; n < 4; ++n)
          acc[m][n] = __builtin_amdgcn_mfma_f32_16x16x32_bf16(a[m], b0[n], acc[m][n], 0, 0, 0);
    }
    const int k2 = (kk + 2) & 7;
    #pragma unroll
    for (int n = 0; n < 4; ++n)
      b0[n] = bp[(k2 * 4 + lg) * NCLS + bbase + n * 16];
    {
      bf16x8 a[4];
      #pragma unroll
      for (int m = 0; m < 4; ++m) a[m] = ap[((kk + 1) * 4 + lg) * 64 + m * 16 + l15];
      #pragma unroll
      for (int m = 0; m < 4; ++m)
        #pragma unroll
        for (int n = 0; n < 4; ++n)
          acc[m][n] = __builtin_amdgcn_mfma_f32_16x16x32_bf16(a[m], b1[n], acc[m][n], 0, 0, 0);
    }
  }

  // epilogue: sims in [-1,1] -> max pass unnecessary
  const int cstar = t >> 1;
  const int wstar = cstar >> 6, nstar = (cstar >> 4) & 3, lstar = cstar & 15;
  #pragma unroll
  for (int m = 0; m < 4; ++m) {
    #pragma unroll
    for (int reg = 0; reg < 4; ++reg) {
      float s = __expf(acc[m][0][reg]) + __expf(acc[m][1][reg]) +
                __expf(acc[m][2][reg]) + __expf(acc[m][3][reg]);
      s += __shfl_xor(s, 1, 64);
      s += __shfl_xor(s, 2, 64);
      s += __shfl_xor(s, 4, 64);
      s += __shfl_xor(s, 8, 64);
      const int r = m * 16 + lg * 4 + reg;
      if (l15 == 0) psum[w][r] = s;
      if (w == wstar && l15 == lstar) simt[r] = acc[m][nstar][reg];
    }
  }
  __syncthreads();
  if (tid < 64) {
    const int r = tid;
    float sum = 0.f;
    #pragma unroll
    for (int ww = 0; ww < 8; ++ww) sum += psum[ww][r];
    float lr = __logf(sum) - simt[r];
    lr += __shfl_xor(lr, 1, 64);
    lr += __shfl_xor(lr, 2, 64);
    lr += __shfl_xor(lr, 4, 64);
    lr += __shfl_xor(lr, 8, 64);
    lr += __shfl_xor(lr, 16, 64);
    lr += __shfl_xor(lr, 32, 64);
    if (tid == 0) atomicAdd(out, lr * (1.0f / (float)NROWS));
  }
}

extern "C" void kernel_launch(void* const* d_in, const int* in_sizes, int n_in,
                              void* d_out, int out_size, void* d_ws, size_t ws_size,
                              hipStream_t stream) {
  const float* x   = (const float*)d_in[0];
  const int*   tgt = (const int*)d_in[1];
  float* ws    = (float*)d_ws;
  int*   cnt   = (int*)ws + WS_CNT_I;
  int*   idx   = (int*)ws + WS_IDX_I;
  u16*   qpack = (u16*)(ws + WS_QPACK_F);
  u16*   xb    = (u16*)(ws + WS_XB_F);
  float* out   = (float*)d_out;

  k_zero<<<1, 512, 0, stream>>>(cnt, out);
  k_scatter<<<NROWS / 256, 256, 0, stream>>>(tgt, cnt, idx);
  k_csum<<<NCLS, 512, 0, stream>>>(x, idx, qpack, xb);
  k_main<<<NBLK, 512, 0, stream>>>(xb, qpack, out);
}

// Round 5
// 79.124 us; speedup vs baseline: 1.2402x; 1.2402x over previous
//
#include <hip/hip_runtime.h>
#include <math.h>

#define NROWS 65536
#define DIM   256
#define NCLS  512
#define CPW   128                 // rows per class
#define BM    64                  // rows per k_main tile
#define NBLK  1024                // NROWS / BM

// ws layout (float offsets)
#define WS_CNT_I   0              // 512 ints
#define WS_IDX_I   512            // 65536 ints
#define WS_QPACK_F 66048          // 131072 u16 (256 KB)

typedef float f32x4  __attribute__((ext_vector_type(4)));
typedef short bf16x8 __attribute__((ext_vector_type(8)));
typedef unsigned short u16;

__device__ inline u16 f2bf(float f) {
  unsigned u = __float_as_uint(f);
  u += 0x7FFFu + ((u >> 16) & 1u);      // RNE (inputs finite)
  return (u16)(u >> 16);
}
__device__ inline unsigned pack2(float a, float b) {
  return (unsigned)f2bf(a) | ((unsigned)f2bf(b) << 16);
}

// ---------------- kernel 0: zero class cursors + output ----------------
__global__ __launch_bounds__(512) void k_zero(int* __restrict__ cnt,
                                              float* __restrict__ out) {
  cnt[threadIdx.x] = 0;
  if (threadIdx.x == 0) out[0] = 0.f;
}

// ---------------- kernel 1: scatter row indices by class ----------------
__global__ __launch_bounds__(256) void k_scatter(
    const int* __restrict__ tgt, int* __restrict__ cnt, int* __restrict__ idx) {
  const int row = blockIdx.x * 256 + threadIdx.x;
  const int c = tgt[row];
  const int p = atomicAdd(&cnt[c], 1);
  if (p < CPW) idx[c * CPW + p] = row;
}

// ---- kernel 2: per-class gather-sum -> normalized prototype B-fragments ----
// Pure streaming: no per-row norms, no intermediate writes. 4 independent
// accumulators to break the FMA dependency chain.
__global__ __launch_bounds__(512) void k_csum(
    const float* __restrict__ x, const int* __restrict__ idx,
    u16* __restrict__ qpack) {
  __shared__ int   sidx[CPW];
  __shared__ float wpart[8][DIM];     // 8 KB
  __shared__ float wsum[4];
  __shared__ float ninv_s;
  const int c    = blockIdx.x;
  const int tid  = threadIdx.x;
  const int w    = tid >> 6;
  const int lane = tid & 63;
  if (tid < CPW) sidx[tid] = idx[c * CPW + tid];
  __syncthreads();

  float4 a4[4];
  #pragma unroll
  for (int j = 0; j < 4; ++j) a4[j] = make_float4(0.f, 0.f, 0.f, 0.f);
  #pragma unroll
  for (int i = 0; i < 4; ++i) {
    #pragma unroll
    for (int j = 0; j < 4; ++j) {
      const int row = sidx[w * 16 + i * 4 + j];
      const float4 v = *reinterpret_cast<const float4*>(
          x + (size_t)row * DIM + lane * 4);
      a4[j].x += v.x; a4[j].y += v.y; a4[j].z += v.z; a4[j].w += v.w;
    }
  }
  float4 vs;
  vs.x = (a4[0].x + a4[1].x) + (a4[2].x + a4[3].x);
  vs.y = (a4[0].y + a4[1].y) + (a4[2].y + a4[3].y);
  vs.z = (a4[0].z + a4[1].z) + (a4[2].z + a4[3].z);
  vs.w = (a4[0].w + a4[1].w) + (a4[2].w + a4[3].w);
  *reinterpret_cast<float4*>(&wpart[w][lane * 4]) = vs;
  __syncthreads();

  float s = 0.f;
  if (tid < DIM) {
    #pragma unroll
    for (int ww = 0; ww < 8; ++ww) s += wpart[ww][tid];
  }
  float sq = s * s;
  sq += __shfl_xor(sq, 1, 64);
  sq += __shfl_xor(sq, 2, 64);
  sq += __shfl_xor(sq, 4, 64);
  sq += __shfl_xor(sq, 8, 64);
  sq += __shfl_xor(sq, 16, 64);
  sq += __shfl_xor(sq, 32, 64);
  if (tid < DIM && (tid & 63) == 0) wsum[tid >> 6] = sq;
  __syncthreads();
  if (tid == 0) ninv_s = rsqrtf(fmaxf(wsum[0] + wsum[1] + wsum[2] + wsum[3], 1e-30f));
  __syncthreads();
  if (tid < DIM)
    qpack[((tid >> 3) * NCLS + c) * 8 + (tid & 7)] = f2bf(s * ninv_s);
}

// --------- kernel 3: fused load+normalize+pack, MFMA GEMM, softmax ----------
// 8 waves, each 64 rows x 64 cols. LDS A layout [kg][row'][8] bf16 (32 KB)
// with XOR swizzle row' = row ^ ((kg>>2)&7):
//   - staging ds_write_b128: per-16-lane cycle covers 32 distinct banks (2-way)
//   - MFMA ds_read_b128: kg>>2 == kk (compile-time), reads stay within the
//     16-row m-block, contiguous per cycle -> conflict-free
__global__ __launch_bounds__(512) void k_main(
    const float* __restrict__ x, const int* __restrict__ tgt,
    const u16* __restrict__ qpack, float* __restrict__ out) {
  __shared__ u16   Alds[32 * 64 * 8] __attribute__((aligned(16)));  // 32 KB
  __shared__ float psum[8][64];
  __shared__ float simt[64];
  __shared__ int   ltgt[64];

  const int tid  = threadIdx.x;
  const int t    = blockIdx.x;
  const int w    = tid >> 6;
  const int lane = tid & 63;

  // ---- stage: load 64x256 f32, row-normalize, pack bf16 -> swizzled LDS
  {
    const int row  = tid >> 3;          // 0..63
    const int part = tid & 7;           // 32 dims each
    const float4* xr = reinterpret_cast<const float4*>(
        x + (size_t)(t * BM + row) * DIM + part * 32);
    float4 v[8];
    #pragma unroll
    for (int j = 0; j < 8; ++j) v[j] = xr[j];
    float ss = 0.f;
    #pragma unroll
    for (int j = 0; j < 8; ++j)
      ss += v[j].x * v[j].x + v[j].y * v[j].y + v[j].z * v[j].z + v[j].w * v[j].w;
    ss += __shfl_xor(ss, 1, 64);
    ss += __shfl_xor(ss, 2, 64);
    ss += __shfl_xor(ss, 4, 64);        // lanes sharing a row differ in bits 0..2
    const float rn = rsqrtf(fmaxf(ss, 1e-30f));
    #pragma unroll
    for (int jj = 0; jj < 4; ++jj) {
      uint4 wv;
      wv.x = pack2(v[2*jj].x * rn,   v[2*jj].y * rn);
      wv.y = pack2(v[2*jj].z * rn,   v[2*jj].w * rn);
      wv.z = pack2(v[2*jj+1].x * rn, v[2*jj+1].y * rn);
      wv.w = pack2(v[2*jj+1].z * rn, v[2*jj+1].w * rn);
      const int kg = part * 4 + jj;
      const int rs = row ^ part;        // (kg>>2)&7 == part
      *reinterpret_cast<uint4*>(&Alds[(kg * 64 + rs) * 8]) = wv;
    }
  }
  if (tid < BM) ltgt[tid] = tgt[t * BM + tid];
  __syncthreads();

  const int lg = lane >> 4, l15 = lane & 15;
  f32x4 acc[4][4];
  #pragma unroll
  for (int m = 0; m < 4; ++m)
    #pragma unroll
    for (int n = 0; n < 4; ++n) acc[m][n] = (f32x4)0.f;

  const bf16x8* bp = reinterpret_cast<const bf16x8*>(qpack);
  const int bbase = w * 64 + l15;       // + n*16 per frag

  bf16x8 b0[4], b1[4];
  #pragma unroll
  for (int n = 0; n < 4; ++n) b0[n] = bp[lg * NCLS + bbase + n * 16];

  #pragma unroll 1
  for (int kk = 0; kk < 8; kk += 2) {
    #pragma unroll
    for (int n = 0; n < 4; ++n)
      b1[n] = bp[((kk + 1) * 4 + lg) * NCLS + bbase + n * 16];
    {
      bf16x8 a[4];
      #pragma unroll
      for (int m = 0; m < 4; ++m)
        a[m] = *reinterpret_cast<const bf16x8*>(
            &Alds[((kk * 4 + lg) * 64 + ((m * 16 + l15) ^ kk)) * 8]);
      #pragma unroll
      for (int m = 0; m < 4; ++m)
        #pragma unroll
        for (int n = 0; n < 4; ++n)
          acc[m][n] = __builtin_amdgcn_mfma_f32_16x16x32_bf16(a[m], b0[n], acc[m][n], 0, 0, 0);
    }
    const int k2 = (kk + 2) & 7;
    #pragma unroll
    for (int n = 0; n < 4; ++n)
      b0[n] = bp[(k2 * 4 + lg) * NCLS + bbase + n * 16];
    {
      bf16x8 a[4];
      #pragma unroll
      for (int m = 0; m < 4; ++m)
        a[m] = *reinterpret_cast<const bf16x8*>(
            &Alds[(((kk + 1) * 4 + lg) * 64 + ((m * 16 + l15) ^ (kk + 1))) * 8]);
      #pragma unroll
      for (int m = 0; m < 4; ++m)
        #pragma unroll
        for (int n = 0; n < 4; ++n)
          acc[m][n] = __builtin_amdgcn_mfma_f32_16x16x32_bf16(a[m], b1[n], acc[m][n], 0, 0, 0);
    }
  }

  // ---- epilogue: sims in [-1,1] -> max pass unnecessary
  #pragma unroll
  for (int m = 0; m < 4; ++m) {
    #pragma unroll
    for (int reg = 0; reg < 4; ++reg) {
      const int r = m * 16 + lg * 4 + reg;
      float s = __expf(acc[m][0][reg]) + __expf(acc[m][1][reg]) +
                __expf(acc[m][2][reg]) + __expf(acc[m][3][reg]);
      s += __shfl_xor(s, 1, 64);
      s += __shfl_xor(s, 2, 64);
      s += __shfl_xor(s, 4, 64);
      s += __shfl_xor(s, 8, 64);
      if (l15 == 0) psum[w][r] = s;
      const int tg = ltgt[r];           // LDS broadcast within lg group
      if (w == (tg >> 6) && l15 == (tg & 15)) {
        const int nt = (tg >> 4) & 3;
        float pv = acc[m][0][reg];
        pv = (nt == 1) ? acc[m][1][reg] : pv;
        pv = (nt == 2) ? acc[m][2][reg] : pv;
        pv = (nt == 3) ? acc[m][3][reg] : pv;
        simt[r] = pv;
      }
    }
  }
  __syncthreads();
  if (tid < 64) {
    float sum = 0.f;
    #pragma unroll
    for (int ww = 0; ww < 8; ++ww) sum += psum[ww][tid];
    float lr = __logf(sum) - simt[tid];
    lr += __shfl_xor(lr, 1, 64);
    lr += __shfl_xor(lr, 2, 64);
    lr += __shfl_xor(lr, 4, 64);
    lr += __shfl_xor(lr, 8, 64);
    lr += __shfl_xor(lr, 16, 64);
    lr += __shfl_xor(lr, 32, 64);
    if (tid == 0) atomicAdd(out, lr * (1.0f / (float)NROWS));
  }
}

extern "C" void kernel_launch(void* const* d_in, const int* in_sizes, int n_in,
                              void* d_out, int out_size, void* d_ws, size_t ws_size,
                              hipStream_t stream) {
  const float* x   = (const float*)d_in[0];
  const int*   tgt = (const int*)d_in[1];
  float* ws    = (float*)d_ws;
  int*   cnt   = (int*)ws + WS_CNT_I;
  int*   idx   = (int*)ws + WS_IDX_I;
  u16*   qpack = (u16*)(ws + WS_QPACK_F);
  float* out   = (float*)d_out;

  k_zero<<<1, 512, 0, stream>>>(cnt, out);
  k_scatter<<<NROWS / 256, 256, 0, stream>>>(tgt, cnt, idx);
  k_csum<<<NCLS, 512, 0, stream>>>(x, idx, qpack);
  k_main<<<NBLK, 512, 0, stream>>>(x, tgt, qpack, out);
}